// Round 1
// baseline (785.645 us; speedup 1.0000x reference)
//
#include <hip/hip_runtime.h>
#include <hip/hip_bf16.h>

#define NB 1024
#define NTOBS 100
#define NT 120
#define ND 256
#define LAT_BSTRIDE (NTOBS * ND)   // 25600
#define OUT_BSTRIDE (NT * ND)      // 30720

typedef __attribute__((ext_vector_type(8))) short bf16x8;
typedef __attribute__((ext_vector_type(4))) float f32x4;

// RTNE float -> bf16 (finite values only; inputs here are bounded)
__device__ __forceinline__ short f2bf(float f) {
    unsigned u = __float_as_uint(f);
    unsigned r = (u + 0x7fffu + ((u >> 16) & 1u)) >> 16;
    return (short)(r & 0xffffu);
}

__device__ __forceinline__ float fast_tanh(float x) {
    float e = __expf(2.0f * x);
    return 1.0f - 2.0f / (e + 1.0f);
}

// ---------------------------------------------------------------------------
// prep: Wt[m][n*256+k] = bf16(W[k][n]) for the 3 layers; plus the two pure
// copy timesteps out[:,0]=lat[:,0], out[:,2]=lat[:,1] (dt==0 quirk in the ref)
// ---------------------------------------------------------------------------
__global__ void prep_kernel(const float* __restrict__ W1,
                            const float* __restrict__ W2,
                            const float* __restrict__ W3,
                            const float* __restrict__ lat,
                            short* __restrict__ wt,
                            float* __restrict__ out)
{
    int tid = blockIdx.x * blockDim.x + threadIdx.x;
    int nth = gridDim.x * blockDim.x;
    for (int i = tid; i < 256 * 256; i += nth) {
        int n = i >> 8, k = i & 255;
        wt[i]               = f2bf(W1[k * 256 + n]);
        wt[i + 65536]       = f2bf(W2[k * 256 + n]);
        wt[i + 2 * 65536]   = f2bf(W3[k * 256 + n]);
    }
    for (int i = tid; i < NB * ND; i += nth) {
        int b = i >> 8, c = i & 255;
        out[(size_t)b * OUT_BSTRIDE + 0 * ND + c] = lat[(size_t)b * LAT_BSTRIDE + 0 * ND + c];
        out[(size_t)b * OUT_BSTRIDE + 2 * ND + c] = lat[(size_t)b * LAT_BSTRIDE + 1 * ND + c];
    }
}

// ---------------------------------------------------------------------------
// One layer: acc[n] (8 col-tiles of 16) = A_rows(16) @ Wt-cols for this wave.
// SRC: 0 = global f32 (stride gstride), 1 = LDS bf16 (swizzled, 512B rows),
//      2 = LDS f32  (swizzled, 1024B rows)
// MFMA 16x16x32 bf16 fragment layouts (m89/m91-verified):
//   A: lane l holds A[l&15][8*(l>>4)+j], B: lane l holds B[8*(l>>4)+j][l&15]
//   D: lane l reg j = D[4*(l>>4)+j][l&15]
// ---------------------------------------------------------------------------
template<int SRC>
__device__ __forceinline__ void layer_mm(f32x4 acc[8],
    const short* __restrict__ wt,
    const float* __restrict__ gA, int gstride,
    const char* __restrict__ ldsA,
    int rh, int ch, int lane)
{
    const int l16 = lane & 15, lgr = lane >> 4;
    const int r = rh * 16 + l16;
#pragma unroll
    for (int n = 0; n < 8; n++) acc[n] = (f32x4){0.f, 0.f, 0.f, 0.f};
#pragma unroll
    for (int kk = 0; kk < 8; kk++) {
        const int k0 = kk * 32 + lgr * 8;
        bf16x8 a;
        if (SRC == 0) {
            const float* p = gA + (size_t)r * gstride + k0;
#pragma unroll
            for (int j = 0; j < 8; j++) a[j] = f2bf(p[j]);
        } else if (SRC == 1) {
            const int off = (r * 512 + k0 * 2) ^ ((r & 7) << 4);
            a = *(const bf16x8*)(ldsA + off);
        } else {
            const int off = (r * 1024 + k0 * 4) ^ ((r & 7) << 5);
            const float* p = (const float*)(ldsA + off);
#pragma unroll
            for (int j = 0; j < 8; j++) a[j] = f2bf(p[j]);
        }
#pragma unroll
        for (int n = 0; n < 8; n++) {
            const int col = ch * 128 + n * 16 + l16;
            bf16x8 b = *(const bf16x8*)(wt + col * 256 + k0);
            acc[n] = __builtin_amdgcn_mfma_f32_16x16x32_bf16(a, b, acc[n], 0, 0, 0);
        }
    }
}

// store tanh(acc + bias) into swizzled bf16 LDS tile ([32 rows][256 cols])
__device__ __forceinline__ void store_h(char* __restrict__ buf, const f32x4 acc[8],
    const float* __restrict__ bias, int rh, int ch, int lane)
{
    const int l16 = lane & 15, lgr = lane >> 4;
#pragma unroll
    for (int n = 0; n < 8; n++) {
        const int c = ch * 128 + n * 16 + l16;
        const float bc = bias[c];
#pragma unroll
        for (int j = 0; j < 4; j++) {
            const int r = rh * 16 + lgr * 4 + j;
            const int off = (r * 512 + c * 2) ^ ((r & 7) << 4);
            *(short*)(buf + off) = f2bf(fast_tanh(acc[n][j] + bc));
        }
    }
}

// ---------------------------------------------------------------------------
// Fused main kernel.
//   blocks [0,32):    sequential rollout k=100..119, 32 rows each (run long,
//                     scheduled first), y kept in f32 LDS
//   blocks [32,3168): one parallel f-eval (k in {1} U {3..99}), 32 rows each
// Block = 256 threads = 4 waves; wave (rh,ch) owns rows rh*16..+15, cols
// ch*128..+127 (8 MFMA col-tiles).
// ---------------------------------------------------------------------------
__global__ __launch_bounds__(256, 2) void ode_main(
    const float* __restrict__ lat, const float* __restrict__ ts,
    const short* __restrict__ wt,
    const float* __restrict__ b1, const float* __restrict__ b2,
    const float* __restrict__ b3, float* __restrict__ out)
{
    __shared__ __align__(16) char s_h[2][32 * 512];   // 2 x 16 KB bf16 h tiles
    __shared__ __align__(16) char s_y[32 * 1024];     // 32 KB f32 y tile (seq only)

    const int tid = threadIdx.x;
    const int lane = tid & 63, wave = tid >> 6;
    const int rh = wave & 1, ch = wave >> 1;
    const int l16 = lane & 15, lgr = lane >> 4;
    const short* wt1 = wt;
    const short* wt2 = wt + 65536;
    const short* wt3 = wt + 2 * 65536;

    if (blockIdx.x < 32) {
        // ---------------- sequential chains ----------------
        const int b0 = blockIdx.x * 32;
        for (int i = tid; i < 32 * 256; i += 256) {
            const int r = i >> 8, c = i & 255;
            const float v = lat[(size_t)(b0 + r) * LAT_BSTRIDE + 99 * ND + c];
            const int off = (r * 1024 + c * 4) ^ ((r & 7) << 5);
            *(float*)(s_y + off) = v;
        }
        __syncthreads();
        for (int step = 0; step < 20; step++) {
            const int k = 100 + step;
            const float dt = ts[k - 1] - ts[k - 2];
            f32x4 acc[8];
            layer_mm<2>(acc, wt1, nullptr, 0, s_y, rh, ch, lane);
            store_h(s_h[0], acc, b1, rh, ch, lane);
            __syncthreads();
            layer_mm<1>(acc, wt2, nullptr, 0, s_h[0], rh, ch, lane);
            store_h(s_h[1], acc, b2, rh, ch, lane);
            __syncthreads();
            layer_mm<1>(acc, wt3, nullptr, 0, s_h[1], rh, ch, lane);
#pragma unroll
            for (int n = 0; n < 8; n++) {
                const int c = ch * 128 + n * 16 + l16;
                const float bc = b3[c];
#pragma unroll
                for (int j = 0; j < 4; j++) {
                    const int r = rh * 16 + lgr * 4 + j;
                    const int yoff = (r * 1024 + c * 4) ^ ((r & 7) << 5);
                    const float yold = *(const float*)(s_y + yoff);
                    const float ynew = yold + (acc[n][j] + bc) * dt;
                    *(float*)(s_y + yoff) = ynew;
                    out[(size_t)(b0 + r) * OUT_BSTRIDE + (size_t)k * ND + c] = ynew;
                }
            }
            __syncthreads();
        }
    } else {
        // ---------------- parallel f-evals ----------------
        const int p = blockIdx.x - 32;
        const int e = p >> 5;        // 0..97
        const int b0 = (p & 31) * 32;
        const int src_t = (e == 0) ? 0 : (e + 1);
        const int out_k = (e == 0) ? 1 : (e + 2);
        const float dt = (e == 0) ? (ts[1] - ts[0]) : (ts[e + 1] - ts[e]);
        const float* ysrc = lat + (size_t)b0 * LAT_BSTRIDE + (size_t)src_t * ND;

        f32x4 acc[8];
        layer_mm<0>(acc, wt1, ysrc, LAT_BSTRIDE, nullptr, rh, ch, lane);
        store_h(s_h[0], acc, b1, rh, ch, lane);
        __syncthreads();
        layer_mm<1>(acc, wt2, nullptr, 0, s_h[0], rh, ch, lane);
        store_h(s_h[1], acc, b2, rh, ch, lane);
        __syncthreads();
        layer_mm<1>(acc, wt3, nullptr, 0, s_h[1], rh, ch, lane);
#pragma unroll
        for (int n = 0; n < 8; n++) {
            const int c = ch * 128 + n * 16 + l16;
            const float bc = b3[c];
#pragma unroll
            for (int j = 0; j < 4; j++) {
                const int r = rh * 16 + lgr * 4 + j;
                const float yold = ysrc[(size_t)r * LAT_BSTRIDE + c];
                out[(size_t)(b0 + r) * OUT_BSTRIDE + (size_t)out_k * ND + c] =
                    yold + (acc[n][j] + bc) * dt;
            }
        }
    }
}

extern "C" void kernel_launch(void* const* d_in, const int* in_sizes, int n_in,
                              void* d_out, int out_size, void* d_ws, size_t ws_size,
                              hipStream_t stream)
{
    const float* lat = (const float*)d_in[0];
    const float* ts  = (const float*)d_in[1];
    // d_in[2] = time_pred (unused: pred steps are exactly indices 100..119)
    const float* W1  = (const float*)d_in[3];
    const float* b1  = (const float*)d_in[4];
    const float* W2  = (const float*)d_in[5];
    const float* b2  = (const float*)d_in[6];
    const float* W3  = (const float*)d_in[7];
    const float* b3  = (const float*)d_in[8];
    float* out = (float*)d_out;
    short* wt = (short*)d_ws;   // 3 * 256*256 bf16 = 384 KB

    hipLaunchKernelGGL(prep_kernel, dim3(256), dim3(256), 0, stream,
                       W1, W2, W3, lat, wt, out);
    // 32 sequential blocks first (long-running), then 98 evals * 32 row-blocks
    hipLaunchKernelGGL(ode_main, dim3(32 + 98 * 32), dim3(256), 0, stream,
                       lat, ts, wt, b1, b2, b3, out);
}

// Round 2
// 179.024 us; speedup vs baseline: 4.3885x; 4.3885x over previous
//
#include <hip/hip_runtime.h>
#include <hip/hip_bf16.h>

#define NB 1024
#define NTOBS 100
#define NT 120
#define ND 256
#define LAT_BSTRIDE (NTOBS * ND)   // 25600
#define OUT_BSTRIDE (NT * ND)      // 30720

#define SEQ_NBLK 64                // 16 rows per seq block
#define PAR_ROWS 128               // rows per parallel block
#define PAR_BLKS (98 * (NB / PAR_ROWS))   // 98 evals * 8 = 784

typedef __attribute__((ext_vector_type(8))) short bf16x8;
typedef __attribute__((ext_vector_type(4))) float f32x4;
typedef __attribute__((ext_vector_type(4))) short short4v;

__device__ __forceinline__ short f2bf(float f) {
    unsigned u = __float_as_uint(f);
    unsigned r = (u + 0x7fffu + ((u >> 16) & 1u)) >> 16;
    return (short)(r & 0xffffu);
}

__device__ __forceinline__ float fast_tanh(float x) {
    float e = __expf(2.0f * x);
    return 1.0f - 2.0f / (e + 1.0f);
}

__device__ __forceinline__ bf16x8 mfma_bf16(bf16x8 a, bf16x8 b); // unused decl guard

// ---------------------------------------------------------------------------
// prep: Wt[m][n*256+k] = bf16(W[k][n]); plus copy steps 0 and 2 (dt==0 quirk)
// ---------------------------------------------------------------------------
__global__ void prep_kernel(const float* __restrict__ W1,
                            const float* __restrict__ W2,
                            const float* __restrict__ W3,
                            const float* __restrict__ lat,
                            short* __restrict__ wt,
                            float* __restrict__ out)
{
    int tid = blockIdx.x * blockDim.x + threadIdx.x;
    int nth = gridDim.x * blockDim.x;
    for (int i = tid; i < 256 * 256; i += nth) {
        int n = i >> 8, k = i & 255;
        wt[i]             = f2bf(W1[k * 256 + n]);
        wt[i + 65536]     = f2bf(W2[k * 256 + n]);
        wt[i + 2 * 65536] = f2bf(W3[k * 256 + n]);
    }
    for (int i = tid; i < NB * ND; i += nth) {
        int b = i >> 8, c = i & 255;
        out[(size_t)b * OUT_BSTRIDE + 0 * ND + c] = lat[(size_t)b * LAT_BSTRIDE + 0 * ND + c];
        out[(size_t)b * OUT_BSTRIDE + 2 * ND + c] = lat[(size_t)b * LAT_BSTRIDE + 1 * ND + c];
    }
}

// ---------------------------------------------------------------------------
// Parallel-path layer: acc[rt][ct] += A(LDS bf16 swizzled) @ Wt(global)
// wave = rg (2 row-groups of 64) x cg (4 col-groups of 64)
// MFMA 16x16x32 bf16: A[l16][lgr*8+j], B[k0+j][l16], D row=4*lgr+j col=l16
// ---------------------------------------------------------------------------
__device__ __forceinline__ void par_layer(f32x4 (&acc)[4][4],
    const char* __restrict__ srcbuf, const short* __restrict__ wtl,
    int rg, int cg, int l16, int lgr)
{
#pragma unroll
    for (int rt = 0; rt < 4; rt++)
#pragma unroll
        for (int ct = 0; ct < 4; ct++)
            acc[rt][ct] = (f32x4){0.f, 0.f, 0.f, 0.f};
#pragma unroll
    for (int kk = 0; kk < 8; kk++) {
        const int k0 = kk * 32 + lgr * 8;
        bf16x8 a[4], b[4];
#pragma unroll
        for (int rt = 0; rt < 4; rt++) {
            const int r = rg * 64 + rt * 16 + l16;
            a[rt] = *(const bf16x8*)(srcbuf + ((r * 512 + k0 * 2) ^ ((r & 7) << 4)));
        }
#pragma unroll
        for (int ct = 0; ct < 4; ct++) {
            const int col = cg * 64 + ct * 16 + l16;
            b[ct] = *(const bf16x8*)(wtl + col * 256 + k0);
        }
#pragma unroll
        for (int rt = 0; rt < 4; rt++)
#pragma unroll
            for (int ct = 0; ct < 4; ct++)
                acc[rt][ct] = __builtin_amdgcn_mfma_f32_16x16x32_bf16(a[rt], b[ct], acc[rt][ct], 0, 0, 0);
    }
}

// tanh(acc + bias) -> swizzled bf16 LDS [128][256]
__device__ __forceinline__ void par_store_h(char* __restrict__ dst,
    const f32x4 (&acc)[4][4], const float bc[4], int rg, int cg, int l16, int lgr)
{
#pragma unroll
    for (int rt = 0; rt < 4; rt++)
#pragma unroll
        for (int ct = 0; ct < 4; ct++) {
            const int c = cg * 64 + ct * 16 + l16;
#pragma unroll
            for (int j = 0; j < 4; j++) {
                const int r = rg * 64 + rt * 16 + lgr * 4 + j;
                const int off = (r * 512 + c * 2) ^ ((r & 7) << 4);
                *(short*)(dst + off) = f2bf(fast_tanh(acc[rt][ct][j] + bc[ct]));
            }
        }
}

// ---------------------------------------------------------------------------
// Fused main kernel, 512 threads (8 waves).
//  blocks [0,64):   sequential chains k=100..119, 16 rows each, weights in regs
//  blocks [64,848): parallel f-evals, 128 rows each
// ---------------------------------------------------------------------------
__global__ __launch_bounds__(512, 2) void ode_main(
    const float* __restrict__ lat, const float* __restrict__ ts,
    const short* __restrict__ wt,
    const float* __restrict__ b1, const float* __restrict__ b2,
    const float* __restrict__ b3, float* __restrict__ out)
{
    __shared__ __align__(16) char smem[131072];

    const int tid = threadIdx.x;
    const int lane = tid & 63, wave = tid >> 6;
    const int l16 = lane & 15, lgr = lane >> 4;
    const short* wt1 = wt;
    const short* wt2 = wt + 65536;
    const short* wt3 = wt + 2 * 65536;

    if (blockIdx.x < SEQ_NBLK) {
        // ================= sequential chains =================
        const int b0 = blockIdx.x * 16;
        char* s_h1 = smem + 16384;   // [16][256] bf16 swizzled (8KB)
        char* s_h2 = smem + 24576;   // s_y = smem: [16][256] f32 swizzled (16KB)

        // per-wave weight slice in registers: cols [32*wave, 32*wave+32)
        bf16x8 w1r[2][8], w2r[2][8], w3r[2][8];
        float bb1[2], bb2[2], bb3[2];
#pragma unroll
        for (int ct = 0; ct < 2; ct++) {
            const int col = wave * 32 + ct * 16 + l16;
            bb1[ct] = b1[col]; bb2[ct] = b2[col]; bb3[ct] = b3[col];
#pragma unroll
            for (int kk = 0; kk < 8; kk++) {
                const int k0 = kk * 32 + lgr * 8;
                w1r[ct][kk] = *(const bf16x8*)(wt1 + col * 256 + k0);
                w2r[ct][kk] = *(const bf16x8*)(wt2 + col * 256 + k0);
                w3r[ct][kk] = *(const bf16x8*)(wt3 + col * 256 + k0);
            }
        }
        // init y tile from lat[:,99,:]
        for (int i = tid; i < 16 * 256 / 4; i += 512) {
            const int r = i >> 6, c = (i & 63) * 4;
            f32x4 v = *(const f32x4*)(lat + (size_t)(b0 + r) * LAT_BSTRIDE + 99 * ND + c);
            *(f32x4*)(smem + ((r * 1024 + c * 4) ^ ((r & 7) << 5))) = v;
        }
        __syncthreads();

#pragma unroll 1
        for (int step = 0; step < 20; step++) {
            const int k = 100 + step;
            const float dt = ts[k - 1] - ts[k - 2];
            f32x4 acc0, acc1;

            // ---- layer 1: A from s_y (f32), W in regs ----
            acc0 = (f32x4){0.f, 0.f, 0.f, 0.f};
            acc1 = (f32x4){0.f, 0.f, 0.f, 0.f};
#pragma unroll
            for (int kk = 0; kk < 8; kk++) {
                const int k0 = kk * 32 + lgr * 8;
                const int off = (l16 * 1024 + k0 * 4) ^ ((l16 & 7) << 5);
                f32x4 lo = *(const f32x4*)(smem + off);
                f32x4 hi = *(const f32x4*)(smem + off + 16);
                bf16x8 a;
                a[0] = f2bf(lo[0]); a[1] = f2bf(lo[1]); a[2] = f2bf(lo[2]); a[3] = f2bf(lo[3]);
                a[4] = f2bf(hi[0]); a[5] = f2bf(hi[1]); a[6] = f2bf(hi[2]); a[7] = f2bf(hi[3]);
                acc0 = __builtin_amdgcn_mfma_f32_16x16x32_bf16(a, w1r[0][kk], acc0, 0, 0, 0);
                acc1 = __builtin_amdgcn_mfma_f32_16x16x32_bf16(a, w1r[1][kk], acc1, 0, 0, 0);
            }
#pragma unroll
            for (int ct = 0; ct < 2; ct++) {
                const f32x4 av = ct ? acc1 : acc0;
                const int c = wave * 32 + ct * 16 + l16;
#pragma unroll
                for (int j = 0; j < 4; j++) {
                    const int r = lgr * 4 + j;
                    *(short*)(s_h1 + ((r * 512 + c * 2) ^ ((r & 7) << 4))) =
                        f2bf(fast_tanh(av[j] + bb1[ct]));
                }
            }
            __syncthreads();

            // ---- layer 2: A from h1 (bf16), W in regs ----
            acc0 = (f32x4){0.f, 0.f, 0.f, 0.f};
            acc1 = (f32x4){0.f, 0.f, 0.f, 0.f};
#pragma unroll
            for (int kk = 0; kk < 8; kk++) {
                const int k0 = kk * 32 + lgr * 8;
                bf16x8 a = *(const bf16x8*)(s_h1 + ((l16 * 512 + k0 * 2) ^ ((l16 & 7) << 4)));
                acc0 = __builtin_amdgcn_mfma_f32_16x16x32_bf16(a, w2r[0][kk], acc0, 0, 0, 0);
                acc1 = __builtin_amdgcn_mfma_f32_16x16x32_bf16(a, w2r[1][kk], acc1, 0, 0, 0);
            }
#pragma unroll
            for (int ct = 0; ct < 2; ct++) {
                const f32x4 av = ct ? acc1 : acc0;
                const int c = wave * 32 + ct * 16 + l16;
#pragma unroll
                for (int j = 0; j < 4; j++) {
                    const int r = lgr * 4 + j;
                    *(short*)(s_h2 + ((r * 512 + c * 2) ^ ((r & 7) << 4))) =
                        f2bf(fast_tanh(av[j] + bb2[ct]));
                }
            }
            __syncthreads();

            // ---- layer 3: A from h2 (bf16), W in regs; y += f*dt ----
            acc0 = (f32x4){0.f, 0.f, 0.f, 0.f};
            acc1 = (f32x4){0.f, 0.f, 0.f, 0.f};
#pragma unroll
            for (int kk = 0; kk < 8; kk++) {
                const int k0 = kk * 32 + lgr * 8;
                bf16x8 a = *(const bf16x8*)(s_h2 + ((l16 * 512 + k0 * 2) ^ ((l16 & 7) << 4)));
                acc0 = __builtin_amdgcn_mfma_f32_16x16x32_bf16(a, w3r[0][kk], acc0, 0, 0, 0);
                acc1 = __builtin_amdgcn_mfma_f32_16x16x32_bf16(a, w3r[1][kk], acc1, 0, 0, 0);
            }
#pragma unroll
            for (int ct = 0; ct < 2; ct++) {
                const f32x4 av = ct ? acc1 : acc0;
                const int c = wave * 32 + ct * 16 + l16;
                const float bc = ct ? bb3[1] : bb3[0];
#pragma unroll
                for (int j = 0; j < 4; j++) {
                    const int r = lgr * 4 + j;
                    const int yoff = (r * 1024 + c * 4) ^ ((r & 7) << 5);
                    const float yold = *(const float*)(smem + yoff);
                    const float ynew = yold + (av[j] + bc) * dt;
                    *(float*)(smem + yoff) = ynew;
                    out[(size_t)(b0 + r) * OUT_BSTRIDE + (size_t)k * ND + c] = ynew;
                }
            }
            __syncthreads();
        }
    } else {
        // ================= parallel f-evals =================
        const int p = blockIdx.x - SEQ_NBLK;
        const int e = p >> 3;                 // 0..97
        const int b0 = (p & 7) * PAR_ROWS;
        const int src_t = (e == 0) ? 0 : (e + 1);
        const int out_k = (e == 0) ? 1 : (e + 2);
        const float dt = (e == 0) ? (ts[1] - ts[0]) : (ts[e + 1] - ts[e]);
        const float* src = lat + (size_t)b0 * LAT_BSTRIDE + (size_t)src_t * ND;

        char* bufA = smem;            // 64KB: A (layer1 src), then h2
        char* bufH = smem + 65536;    // 64KB: h1
        const int rg = wave >> 2, cg = wave & 3;

        // stage A = bf16(y) into bufA, swizzled
        for (int i = tid; i < PAR_ROWS * ND / 4; i += 512) {
            const int r = i >> 6, c = (i & 63) * 4;
            f32x4 v = *(const f32x4*)(src + (size_t)r * LAT_BSTRIDE + c);
            short4v s;
            s[0] = f2bf(v[0]); s[1] = f2bf(v[1]); s[2] = f2bf(v[2]); s[3] = f2bf(v[3]);
            *(short4v*)(bufA + ((r * 512 + c * 2) ^ ((r & 7) << 4))) = s;
        }
        __syncthreads();

        f32x4 acc[4][4];
        float bc[4];

        // layer 1: bufA -> bufH
#pragma unroll
        for (int ct = 0; ct < 4; ct++) bc[ct] = b1[cg * 64 + ct * 16 + l16];
        par_layer(acc, bufA, wt1, rg, cg, l16, lgr);
        par_store_h(bufH, acc, bc, rg, cg, l16, lgr);
        __syncthreads();

        // layer 2: bufH -> bufA (h2 overwrites A)
#pragma unroll
        for (int ct = 0; ct < 4; ct++) bc[ct] = b2[cg * 64 + ct * 16 + l16];
        par_layer(acc, bufH, wt2, rg, cg, l16, lgr);
        par_store_h(bufA, acc, bc, rg, cg, l16, lgr);
        __syncthreads();

        // layer 3: bufA -> epilogue
#pragma unroll
        for (int ct = 0; ct < 4; ct++) bc[ct] = b3[cg * 64 + ct * 16 + l16];
        par_layer(acc, bufA, wt3, rg, cg, l16, lgr);
#pragma unroll
        for (int rt = 0; rt < 4; rt++)
#pragma unroll
            for (int ct = 0; ct < 4; ct++) {
                const int c = cg * 64 + ct * 16 + l16;
#pragma unroll
                for (int j = 0; j < 4; j++) {
                    const int r = rg * 64 + rt * 16 + lgr * 4 + j;
                    const float yold = src[(size_t)r * LAT_BSTRIDE + c];
                    out[(size_t)(b0 + r) * OUT_BSTRIDE + (size_t)out_k * ND + c] =
                        yold + (acc[rt][ct][j] + bc[ct]) * dt;
                }
            }
    }
}

extern "C" void kernel_launch(void* const* d_in, const int* in_sizes, int n_in,
                              void* d_out, int out_size, void* d_ws, size_t ws_size,
                              hipStream_t stream)
{
    const float* lat = (const float*)d_in[0];
    const float* ts  = (const float*)d_in[1];
    // d_in[2] = time_pred (unused: pred steps are exactly indices 100..119)
    const float* W1  = (const float*)d_in[3];
    const float* b1  = (const float*)d_in[4];
    const float* W2  = (const float*)d_in[5];
    const float* b2  = (const float*)d_in[6];
    const float* W3  = (const float*)d_in[7];
    const float* b3  = (const float*)d_in[8];
    float* out = (float*)d_out;
    short* wt = (short*)d_ws;   // 3 * 256*256 bf16 = 384 KB

    hipLaunchKernelGGL(prep_kernel, dim3(256), dim3(256), 0, stream,
                       W1, W2, W3, lat, wt, out);
    hipLaunchKernelGGL(ode_main, dim3(SEQ_NBLK + PAR_BLKS), dim3(512), 0, stream,
                       lat, ts, wt, b1, b2, b3, out);
}